// Round 2
// baseline (231.345 us; speedup 1.0000x reference)
//
#include <hip/hip_runtime.h>

// SPGG Q-learning step on a 2048x2048 torus — 4 cells per thread, vectorized.
// Outputs (concatenated float32 in d_out): Q_new [N*4], type_t1 [N], profit [N].
// Workspace: pm (fermi profit matrix = upd) [N floats].
//
// Numerics: f32 ops feeding the fermi decision use __f*_rn intrinsics in the
// reference's exact evaluation order (no FMA contraction / reassociation);
// exp computed in double, rounded once -> correctly-rounded f32 exp.

#define LSIDE 2048
#define LMASK 2047
#define LSHIFT 11
#define NCELL (LSIDE * LSIDE)

__global__ __launch_bounds__(256) void spgg_k1(
    const int* __restrict__ tmin,   // type_t_minus
    const int* __restrict__ tt,     // type_t
    const float* __restrict__ Q,    // Q_tensor [N,4]
    float* __restrict__ Qn,         // out: Q_new [N,4]
    float* __restrict__ prof,       // out: profit [N]
    float* __restrict__ pm)         // ws:  fermi profit matrix [N]
{
    int tid   = blockIdx.x * blockDim.x + threadIdx.x;
    int cell0 = tid << 2;                 // 4 consecutive cells, same row
    int i  = cell0 >> LSHIFT;
    int j0 = cell0 & LMASK;               // j0 % 4 == 0

    int im1 = (i - 1) & LMASK, ip1 = (i + 1) & LMASK;
    int im2 = (i - 2) & LMASK, ip2 = (i + 2) & LMASK;
    int jm2 = (j0 - 2) & LMASK;           // even -> int2-aligned
    int jm1 = (j0 - 1) & LMASK;
    int jp4 = (j0 + 4) & LMASK;           // multiple of 4

    const int4* tt4 = (const int4*)tt;
    const int2* tt2 = (const int2*)tt;

    // row i: cols j0-2 .. j0+5
    int4 rc  = tt4[((i << LSHIFT) | j0) >> 2];
    int2 rcl = tt2[((i << LSHIFT) | jm2) >> 1];
    int2 rcr = tt2[((i << LSHIFT) | jp4) >> 1];
    // rows i±1: cols j0-1 .. j0+4
    int4 ru  = tt4[((im1 << LSHIFT) | j0) >> 2];
    int  rul = tt[(im1 << LSHIFT) | jm1];
    int  rur = tt[(im1 << LSHIFT) | jp4];
    int4 rd  = tt4[((ip1 << LSHIFT) | j0) >> 2];
    int  rdl = tt[(ip1 << LSHIFT) | jm1];
    int  rdr = tt[(ip1 << LSHIFT) | jp4];
    // rows i±2: cols j0 .. j0+3
    int4 ruu = tt4[((im2 << LSHIFT) | j0) >> 2];
    int4 rdd = tt4[((ip2 << LSHIFT) | j0) >> 2];

    // cooperator masks (c == 1)
    int r0[8]  = {rcl.x == 1, rcl.y == 1, rc.x == 1, rc.y == 1,
                  rc.z == 1, rc.w == 1, rcr.x == 1, rcr.y == 1}; // j0-2..j0+5
    int rm[6]  = {rul == 1, ru.x == 1, ru.y == 1, ru.z == 1, ru.w == 1, rur == 1}; // j0-1..j0+4
    int rp[6]  = {rdl == 1, rd.x == 1, rd.y == 1, rd.z == 1, rd.w == 1, rdr == 1};
    int ru2[4] = {ruu.x == 1, ruu.y == 1, ruu.z == 1, ruu.w == 1};   // j0..j0+3
    int rd2[4] = {rdd.x == 1, rdd.y == 1, rdd.z == 1, rdd.w == 1};
    int vtt[4] = {rc.x, rc.y, rc.z, rc.w};   // raw type_t (current action B)

    int4 tm4 = ((const int4*)tmin)[tid];
    int tmv[4] = {tm4.x, tm4.y, tm4.z, tm4.w};

    float prof_[4], pm_[4];

    const float KB        = 0.5554f;  // float32(R / 5.0)
    const float ETA       = 0.8f;
    const float ONE_M_ETA = 0.2f;
    const float GAMMA     = 0.8f;

#pragma unroll
    for (int t = 0; t < 4; ++t) {
        int c_cc = r0[t + 2];
        int cn_c = c_cc + rm[t + 1] + rp[t + 1] + r0[t + 1] + r0[t + 3];
        int cn_u = rm[t + 1] + ru2[t] + c_cc + rm[t] + rm[t + 2];
        int cn_d = rp[t + 1] + c_cc + rd2[t] + rp[t] + rp[t + 2];
        int cn_l = r0[t + 1] + rm[t] + rp[t] + r0[t] + c_cc;
        int cn_r = r0[t + 3] + rm[t + 2] + rp[t + 2] + c_cc + r0[t + 4];

        float b_c = __fmul_rn((float)cn_c, KB);
        float b_u = __fmul_rn((float)cn_u, KB);
        float b_d = __fmul_rn((float)cn_d, KB);
        float b_l = __fmul_rn((float)cn_l, KB);
        float b_r = __fmul_rn((float)cn_r, KB);

        float s0 = __fadd_rn(__fadd_rn(__fadd_rn(__fadd_rn(b_c, b_u), b_d), b_l), b_r);
        float s1 = __fadd_rn(__fadd_rn(__fadd_rn(__fadd_rn(
                       __fsub_rn(b_c, 1.0f), __fsub_rn(b_u, 1.0f)),
                       __fsub_rn(b_d, 1.0f)), __fsub_rn(b_l, 1.0f)),
                       __fsub_rn(b_r, 1.0f));
        float profit = c_cc ? s1 : s0;

        float4 qr = ((const float4*)Q)[cell0 + t];
        int B = vtt[t];
        int A = tmv[t];
        float q0 = (B == 0) ? qr.x : qr.z;
        float q1 = (B == 0) ? qr.y : qr.w;
        float mx = fmaxf(q0, q1);
        int k = A * 2 + B;
        float old = (k == 0) ? qr.x : ((k == 1) ? qr.y : ((k == 2) ? qr.z : qr.w));

        float t0v = __fmul_rn(GAMMA, mx);
        float t1v = __fadd_rn(profit, t0v);
        float t2v = __fmul_rn(ETA, t1v);
        float t3v = __fmul_rn(ONE_M_ETA, old);
        float upd = __fadd_rn(t3v, t2v);

        float4 qo;
        qo.x = (k == 0) ? upd : qr.x;
        qo.y = (k == 1) ? upd : qr.y;
        qo.z = (k == 2) ? upd : qr.z;
        qo.w = (k == 3) ? upd : qr.w;
        ((float4*)Qn)[cell0 + t] = qo;

        prof_[t] = profit;
        pm_[t]   = upd;
    }

    ((float4*)prof)[tid] = make_float4(prof_[0], prof_[1], prof_[2], prof_[3]);
    ((float4*)pm)[tid]   = make_float4(pm_[0], pm_[1], pm_[2], pm_[3]);
}

__global__ __launch_bounds__(256) void spgg_k2(
    const int* __restrict__ tt,
    const int* __restrict__ ldir,
    const float* __restrict__ lp,
    const float* __restrict__ pm,
    float* __restrict__ t1out)
{
    int tid   = blockIdx.x * blockDim.x + threadIdx.x;
    int cell0 = tid << 2;
    int i  = cell0 >> LSHIFT;
    int j0 = cell0 & LMASK;

    int4   dir4 = ((const int4*)ldir)[tid];
    float4 lp4  = ((const float4*)lp)[tid];
    int4   ttc4 = ((const int4*)tt)[tid];
    float4 pm4  = ((const float4*)pm)[tid];

    int   dirs[4] = {dir4.x, dir4.y, dir4.z, dir4.w};
    float lps[4]  = {lp4.x, lp4.y, lp4.z, lp4.w};
    int   ttc[4]  = {ttc4.x, ttc4.y, ttc4.z, ttc4.w};
    float pmc[4]  = {pm4.x, pm4.y, pm4.z, pm4.w};

    float outv[4];
#pragma unroll
    for (int t = 0; t < 4; ++t) {
        int j   = j0 + t;
        int dir = dirs[t];
        // dir: 0=left(j-1) 1=right(j+1) 2=up(i-1) 3=down(i+1)
        int ni = (i + ((dir == 3) - (dir == 2))) & LMASK;
        int nj = (j + ((dir == 1) - (dir == 0))) & LMASK;
        int nidx = (ni << LSHIFT) | nj;

        float pmn = pm[nidx];
        int   ttn = tt[nidx];

        float e1 = __fsub_rn(pmc[t], pmn);
        float e2 = __fmul_rn(e1, 2.0f);          // / K_FERMI(0.5) exactly
        float ex = (float)exp((double)e2);       // correctly-rounded f32 exp
        float W  = __fdiv_rn(1.0f, __fadd_rn(1.0f, ex));
        outv[t] = (float)((lps[t] <= W) ? ttn : ttc[t]);
    }

    ((float4*)t1out)[tid] = make_float4(outv[0], outv[1], outv[2], outv[3]);
}

extern "C" void kernel_launch(void* const* d_in, const int* in_sizes, int n_in,
                              void* d_out, int out_size, void* d_ws, size_t ws_size,
                              hipStream_t stream) {
    const int*   type_t_minus = (const int*)d_in[0];
    const int*   type_t       = (const int*)d_in[1];
    const float* Q_tensor     = (const float*)d_in[2];
    const int*   ldir         = (const int*)d_in[3];
    const float* lprob        = (const float*)d_in[4];

    float* out   = (float*)d_out;
    float* Qn    = out;                       // [N*4]
    float* t1out = out + (size_t)4 * NCELL;   // [N]
    float* prof  = out + (size_t)5 * NCELL;   // [N]
    float* pm    = (float*)d_ws;              // [N] floats (16 MiB)

    const int threads = 256;
    const int blocks  = NCELL / (threads * 4);  // 4096
    spgg_k1<<<blocks, threads, 0, stream>>>(type_t_minus, type_t, Q_tensor,
                                            Qn, prof, pm);
    spgg_k2<<<blocks, threads, 0, stream>>>(type_t, ldir, lprob, pm, t1out);
}

// Round 3
// 216.481 us; speedup vs baseline: 1.0687x; 1.0687x over previous
//
#include <hip/hip_runtime.h>

// SPGG Q-learning step on a 2048x2048 torus — SINGLE fused kernel.
//
// Key idea: upd (the fermi profit matrix pm) is a pure function of the inputs
// (radius-2 tt stencil, one Q row, one tmin entry). So instead of a two-kernel
// producer/consumer through workspace, each thread recomputes its selected
// NEIGHBOR's upd locally — bit-identically (same __f*_rn op sequence) — and
// the fermi update fuses into the same kernel. No workspace, one launch.
//
// tt is staged per-block in LDS (rows i-3..i+3, cols j0-4..j0+259, wrapped)
// with coalesced int4 loads; all per-cell global accesses are 1-cell/thread
// fully coalesced (the round-2 lane-strided layout regressed).
//
// Numerics: f32 ops feeding the fermi decision use __f*_rn intrinsics in the
// reference's exact evaluation order; exp in double, rounded once (identical
// to the passing rounds 1-2).

#define LSIDE 2048
#define LMASK 2047
#define LSHIFT 11
#define NCELL (LSIDE * LSIDE)

#define TROWS 7
#define TCOLS 264   // 256 + 2*4 halo (4-aligned); 264*4B row = 16B-aligned

__global__ __launch_bounds__(256) void spgg_fused(
    const int* __restrict__ tmin,   // type_t_minus
    const int* __restrict__ tt,     // type_t
    const float* __restrict__ Q,    // Q_tensor [N,4]
    const int* __restrict__ ldir,   // learning_direction
    const float* __restrict__ lp,   // learning_probabilities
    float* __restrict__ Qn,         // out: Q_new [N,4]
    float* __restrict__ prof,       // out: profit [N]
    float* __restrict__ t1out)      // out: type_t1 [N]
{
    __shared__ int tile[TROWS][TCOLS];

    const int t   = threadIdx.x;
    const int blk = blockIdx.x;
    const int i   = blk >> 3;            // 8 blocks per lattice row
    const int j0  = (blk & 7) << 8;      // 256 cells per block

    // ---- stage tt tile + halo into LDS (coalesced int4, wrapped) ----
    for (int k = t; k < TROWS * (TCOLS / 4); k += 256) {
        int r = k / (TCOLS / 4);
        int m = k - r * (TCOLS / 4);
        int row_g = (i + r - 3) & LMASK;
        int col_g = (j0 - 4 + (m << 2)) & LMASK;   // multiple of 4 -> aligned
        int4 v = *(const int4*)&tt[(row_g << LSHIFT) + col_g];
        *(int4*)&tile[r][m << 2] = v;
    }
    __syncthreads();

    const float KB        = 0.5554f;  // float32(R / 5.0)
    const float ETA       = 0.8f;
    const float ONE_M_ETA = 0.2f;     // float32(1.0 - 0.8)
    const float GAMMA     = 0.8f;

    // cooperator mask from LDS
#define M(r, c) (tile[r][c] == 1)

    // profit at local tile coords (r,c) — exact reference op order.
    auto profit_at = [&](int r, int c) -> float {
        int m_cc = M(r, c);
        int cn_c = m_cc + M(r-1, c) + M(r+1, c) + M(r, c-1) + M(r, c+1);
        int cn_u = M(r-1, c) + M(r-2, c) + m_cc + M(r-1, c-1) + M(r-1, c+1);
        int cn_d = M(r+1, c) + m_cc + M(r+2, c) + M(r+1, c-1) + M(r+1, c+1);
        int cn_l = M(r, c-1) + M(r-1, c-1) + M(r+1, c-1) + M(r, c-2) + m_cc;
        int cn_r = M(r, c+1) + M(r-1, c+1) + M(r+1, c+1) + m_cc + M(r, c+2);
        float b_c = __fmul_rn((float)cn_c, KB);
        float b_u = __fmul_rn((float)cn_u, KB);
        float b_d = __fmul_rn((float)cn_d, KB);
        float b_l = __fmul_rn((float)cn_l, KB);
        float b_r = __fmul_rn((float)cn_r, KB);
        float s0 = __fadd_rn(__fadd_rn(__fadd_rn(__fadd_rn(b_c, b_u), b_d), b_l), b_r);
        float s1 = __fadd_rn(__fadd_rn(__fadd_rn(__fadd_rn(
                       __fsub_rn(b_c, 1.0f), __fsub_rn(b_u, 1.0f)),
                       __fsub_rn(b_d, 1.0f)), __fsub_rn(b_l, 1.0f)),
                       __fsub_rn(b_r, 1.0f));
        return m_cc ? s1 : s0;
    };

    // Q-learning update value — exact reference op order.
    auto upd_of = [&](float profit, float4 qr, int A, int B) -> float {
        float q0 = (B == 0) ? qr.x : qr.z;
        float q1 = (B == 0) ? qr.y : qr.w;
        float mx = fmaxf(q0, q1);
        int k = A * 2 + B;
        float old = (k == 0) ? qr.x : ((k == 1) ? qr.y : ((k == 2) ? qr.z : qr.w));
        float t0 = __fmul_rn(GAMMA, mx);
        float t1 = __fadd_rn(profit, t0);
        float t2 = __fmul_rn(ETA, t1);
        float t3 = __fmul_rn(ONE_M_ETA, old);
        return __fadd_rn(t3, t2);
    };

    const int j   = j0 + t;
    const int idx = (i << LSHIFT) + j;
    const int lr  = 3, lc = t + 4;

    // ---- own cell: profit + Q update ----
    float p_own = profit_at(lr, lc);
    float4 qr   = ((const float4*)Q)[idx];
    int B = tile[lr][lc];
    int A = tmin[idx];
    float upd = upd_of(p_own, qr, A, B);

    int k = A * 2 + B;
    float4 qo;
    qo.x = (k == 0) ? upd : qr.x;
    qo.y = (k == 1) ? upd : qr.y;
    qo.z = (k == 2) ? upd : qr.z;
    qo.w = (k == 3) ? upd : qr.w;
    ((float4*)Qn)[idx] = qo;
    prof[idx] = p_own;

    // ---- fermi: recompute the selected neighbor's upd, bit-identically ----
    int dir = ldir[idx];
    // dir: 0=left(j-1) 1=right(j+1) 2=up(i-1) 3=down(i+1)
    int di = (dir == 3) - (dir == 2);
    int dj = (dir == 1) - (dir == 0);
    int ni = (i + di) & LMASK;
    int nj = (j + dj) & LMASK;
    int nidx = (ni << LSHIFT) + nj;

    float p_nb  = profit_at(lr + di, lc + dj);
    float4 qn4  = ((const float4*)Q)[nidx];   // gather, adjacent -> L2-hit
    int Bn = tile[lr + di][lc + dj];
    int An = tmin[nidx];
    float upd_nb = upd_of(p_nb, qn4, An, Bn);

    float e1 = __fsub_rn(upd, upd_nb);
    float e2 = __fmul_rn(e1, 2.0f);           // / K_FERMI(0.5) exactly
    float ex = (float)exp((double)e2);        // same as passing rounds
    float W  = __fdiv_rn(1.0f, __fadd_rn(1.0f, ex));
    float pv = lp[idx];
    int sel = (pv <= W) ? Bn : B;
    t1out[idx] = (float)sel;
#undef M
}

extern "C" void kernel_launch(void* const* d_in, const int* in_sizes, int n_in,
                              void* d_out, int out_size, void* d_ws, size_t ws_size,
                              hipStream_t stream) {
    const int*   type_t_minus = (const int*)d_in[0];
    const int*   type_t       = (const int*)d_in[1];
    const float* Q_tensor     = (const float*)d_in[2];
    const int*   ldir         = (const int*)d_in[3];
    const float* lprob        = (const float*)d_in[4];

    float* out   = (float*)d_out;
    float* Qn    = out;                       // [N*4]
    float* t1out = out + (size_t)4 * NCELL;   // [N]
    float* prof  = out + (size_t)5 * NCELL;   // [N]

    const int threads = 256;
    const int blocks  = NCELL / threads;      // 16384 (8 blocks per row)
    spgg_fused<<<blocks, threads, 0, stream>>>(type_t_minus, type_t, Q_tensor,
                                               ldir, lprob, Qn, prof, t1out);
}